// Round 1
// baseline (76.813 us; speedup 1.0000x reference)
//
#include <hip/hip_runtime.h>

constexpr int NTOK = 262144;
constexpr int D    = 64;   // CODE_DIM
constexpr int K    = 16;   // NUM_CODES

__global__ __launch_bounds__(256) void quantizer_kernel(
    const float* __restrict__ x, const float* __restrict__ cb, float* __restrict__ out)
{
    const int t = blockIdx.x * blockDim.x + threadIdx.x;
    if (t >= NTOK) return;

    // ---- load this token's 64 floats into registers (16x float4) ----
    const float4* __restrict__ X4 = reinterpret_cast<const float4*>(x) + (size_t)t * (D / 4);
    float4 xr[D / 4];
#pragma unroll
    for (int q = 0; q < D / 4; ++q) xr[q] = X4[q];

    const float4* __restrict__ CB4 = reinterpret_cast<const float4*>(cb);

    // ---- distances: fp32 16-term partials, fp64 accumulate; first-min argmin ----
    double best = 1e300;
    int bidx = 0;
#pragma unroll
    for (int k = 0; k < K; ++k) {
        double a = 0.0;
#pragma unroll
        for (int b = 0; b < 4; ++b) {
            float p = 0.f;
#pragma unroll
            for (int j = 0; j < 4; ++j) {
                // uniform (k,b,j) -> scalar loads through K$, no LDS needed
                float4 c  = CB4[k * (D / 4) + b * 4 + j];
                float4 xv = xr[b * 4 + j];
                float d0 = xv.x - c.x, d1 = xv.y - c.y;
                float d2 = xv.z - c.z, d3 = xv.w - c.w;
                p = fmaf(d0, d0, p);
                p = fmaf(d1, d1, p);
                p = fmaf(d2, d2, p);
                p = fmaf(d3, d3, p);
            }
            a += (double)p;
        }
        if (a < best) { best = a; bidx = k; }  // strict <: numpy first-occurrence argmin
    }

    // ---- one-hot: out[0 .. N*16) ----
    float* oh = out + (size_t)t * K;
#pragma unroll
    for (int q = 0; q < K / 4; ++q) {
        float4 v;
        v.x = (bidx == q * 4 + 0) ? 1.f : 0.f;
        v.y = (bidx == q * 4 + 1) ? 1.f : 0.f;
        v.z = (bidx == q * 4 + 2) ? 1.f : 0.f;
        v.w = (bidx == q * 4 + 3) ? 1.f : 0.f;
        reinterpret_cast<float4*>(oh)[q] = v;
    }

    // ---- residual: out[N*16 .. N*16 + N*64) ----
    float* res = out + (size_t)NTOK * K + (size_t)t * D;
#pragma unroll
    for (int q = 0; q < D / 4; ++q) {
        float4 c  = CB4[bidx * (D / 4) + q];  // per-lane idx -> vector load, 4KB L1-resident
        float4 xv = xr[q];
        float4 r;
        r.x = xv.x - c.x; r.y = xv.y - c.y;
        r.z = xv.z - c.z; r.w = xv.w - c.w;
        reinterpret_cast<float4*>(res)[q] = r;
    }
}

extern "C" void kernel_launch(void* const* d_in, const int* in_sizes, int n_in,
                              void* d_out, int out_size, void* d_ws, size_t ws_size,
                              hipStream_t stream) {
    const float* x  = (const float*)d_in[0];   // [262144, 64] fp32
    const float* cb = (const float*)d_in[1];   // [16, 64] fp32
    float* out = (float*)d_out;                // [N*16 onehot | N*64 residual] fp32

    const int threads = 256;
    const int blocks  = NTOK / threads;        // 1024
    quantizer_kernel<<<blocks, threads, 0, stream>>>(x, cb, out);
}

// Round 2
// 52.697 us; speedup vs baseline: 1.4576x; 1.4576x over previous
//
#include <hip/hip_runtime.h>

constexpr int NTOK = 262144;
constexpr int D    = 64;   // CODE_DIM
constexpr int K    = 16;   // NUM_CODES
constexpr int TPB  = 256;  // threads == tokens per block

__global__ __launch_bounds__(TPB) void quantizer_kernel(
    const float* __restrict__ x, const float* __restrict__ cb, float* __restrict__ out)
{
    __shared__ float4 s4[TPB * (D / 4)];   // 64 KiB staging (residual, then onehot)
    const int tid = threadIdx.x;
    const int t   = blockIdx.x * TPB + tid;

    // ---- token's 64 floats into registers (strided reads; lines fully consumed -> fetch OK) ----
    const float4* __restrict__ X4 = reinterpret_cast<const float4*>(x) + (size_t)t * (D / 4);
    float4 xr[D / 4];
#pragma unroll
    for (int q = 0; q < D / 4; ++q) xr[q] = X4[q];

    const float4* __restrict__ CB4 = reinterpret_cast<const float4*>(cb);

    // ---- distances: fp32 16-term partials, fp64 accumulate; strict-< first-occurrence argmin ----
    double best = 1e300;
    int bidx = 0;
#pragma unroll
    for (int k = 0; k < K; ++k) {
        double a = 0.0;
#pragma unroll
        for (int b = 0; b < 4; ++b) {
            float p = 0.f;
#pragma unroll
            for (int j = 0; j < 4; ++j) {
                float4 c  = CB4[k * (D / 4) + b * 4 + j];   // wave-uniform -> scalar K$ loads
                float4 xv = xr[b * 4 + j];
                float d0 = xv.x - c.x, d1 = xv.y - c.y;
                float d2 = xv.z - c.z, d3 = xv.w - c.w;
                p = fmaf(d0, d0, p);
                p = fmaf(d1, d1, p);
                p = fmaf(d2, d2, p);
                p = fmaf(d3, d3, p);
            }
            a += (double)p;
        }
        if (a < best) { best = a; bidx = k; }
    }

    float4* __restrict__ out4 = reinterpret_cast<float4*>(out);

    // ---- residual -> LDS (XOR-swizzled slots: 256B-stride writes conflict-free) ----
#pragma unroll
    for (int q = 0; q < D / 4; ++q) {
        float4 c  = CB4[bidx * (D / 4) + q];   // 4 KiB codebook, L1-resident
        float4 xv = xr[q];
        float4 r;
        r.x = xv.x - c.x; r.y = xv.y - c.y;
        r.z = xv.z - c.z; r.w = xv.w - c.w;
        s4[tid * (D / 4) + (q ^ (tid & 15))] = r;
    }
    __syncthreads();
    {   // coalesced store: block writes contiguous 64 KiB, 4 KiB per iteration
        const size_t base = (size_t)NTOK * (K / 4) + (size_t)blockIdx.x * TPB * (D / 4);
#pragma unroll
        for (int it = 0; it < D / 4; ++it) {
            int i   = it * TPB + tid;
            int tok = i >> 4, qq = i & 15;
            out4[base + i] = s4[tok * (D / 4) + (qq ^ (tok & 15))];
        }
    }
    __syncthreads();

    // ---- onehot -> LDS (64B stride = 2-way conflict, free), coalesced 16 KiB store ----
#pragma unroll
    for (int q = 0; q < K / 4; ++q) {
        float4 v;
        v.x = (bidx == q * 4 + 0) ? 1.f : 0.f;
        v.y = (bidx == q * 4 + 1) ? 1.f : 0.f;
        v.z = (bidx == q * 4 + 2) ? 1.f : 0.f;
        v.w = (bidx == q * 4 + 3) ? 1.f : 0.f;
        s4[tid * (K / 4) + q] = v;
    }
    __syncthreads();
    {
        const size_t base = (size_t)blockIdx.x * TPB * (K / 4);
#pragma unroll
        for (int it = 0; it < K / 4; ++it) {
            int i = it * TPB + tid;
            out4[base + i] = s4[i];
        }
    }
}

extern "C" void kernel_launch(void* const* d_in, const int* in_sizes, int n_in,
                              void* d_out, int out_size, void* d_ws, size_t ws_size,
                              hipStream_t stream) {
    const float* x  = (const float*)d_in[0];   // [262144, 64] fp32
    const float* cb = (const float*)d_in[1];   // [16, 64] fp32
    float* out = (float*)d_out;                // [N*16 onehot | N*64 residual] fp32

    quantizer_kernel<<<NTOK / TPB, TPB, 0, stream>>>(x, cb, out);
}

// Round 3
// 51.298 us; speedup vs baseline: 1.4974x; 1.0273x over previous
//
#include <hip/hip_runtime.h>

constexpr int NTOK = 262144;
constexpr int D    = 64;   // CODE_DIM
constexpr int K    = 16;   // NUM_CODES
constexpr int TPB  = 128;  // threads == tokens per block
constexpr int ROW4 = D / 4;          // 16 float4 per token row
constexpr int NF4  = TPB * ROW4;     // 2048 float4 = 32 KiB staging

__global__ __launch_bounds__(TPB) void quantizer_kernel(
    const float* __restrict__ x, const float* __restrict__ cb, float* __restrict__ out)
{
    __shared__ float4 s4[NF4];       // 32 KiB: input staging, then residual
    const int tid = threadIdx.x;
    const size_t blk4 = (size_t)blockIdx.x * NF4;   // block's float4 offset

    const float4* __restrict__ X4  = reinterpret_cast<const float4*>(x);
    const float4* __restrict__ CB4 = reinterpret_cast<const float4*>(cb);
    float4* __restrict__ out4      = reinterpret_cast<float4*>(out);

    // ---- Phase 0: coalesced global->LDS (1KiB/wave/instr), XOR-swizzled dst ----
    // LDS slot for (tok, q) = tok*16 + (q ^ (tok&15))
#pragma unroll
    for (int it = 0; it < ROW4; ++it) {
        int i   = it * TPB + tid;            // linear float4 index within block
        int tok = i >> 4, q = i & 15;
        s4[(tok << 4) + (q ^ (tok & 15))] = X4[blk4 + i];
    }
    __syncthreads();

    // ---- Phase 1: own token row LDS->regs (swizzle => uniform 8/bank, conflict-free) ----
    float4 xr[ROW4];
#pragma unroll
    for (int q = 0; q < ROW4; ++q)
        xr[q] = s4[(tid << 4) + (q ^ (tid & 15))];

    // ---- distances: fp32 seq partials over 16-elem blocks, f64 accumulate;
    //      strict-< first-occurrence argmin (bit-identical to R2, absmax==0) ----
    double best = 1e300;
    int bidx = 0;
#pragma unroll
    for (int k = 0; k < K; ++k) {
        double a = 0.0;
#pragma unroll
        for (int b = 0; b < 4; ++b) {
            float p = 0.f;
#pragma unroll
            for (int j = 0; j < 4; ++j) {
                float4 c  = CB4[k * ROW4 + b * 4 + j];   // wave-uniform -> scalar K$
                float4 xv = xr[b * 4 + j];
                float d0 = xv.x - c.x, d1 = xv.y - c.y;
                float d2 = xv.z - c.z, d3 = xv.w - c.w;
                p = fmaf(d0, d0, p);
                p = fmaf(d1, d1, p);
                p = fmaf(d2, d2, p);
                p = fmaf(d3, d3, p);
            }
            a += (double)p;
        }
        if (a < best) { best = a; bidx = k; }
    }

    // ---- Phase 2: residual into own row slots (self-only: no barrier needed) ----
#pragma unroll
    for (int q = 0; q < ROW4; ++q) {
        float4 c  = CB4[bidx * ROW4 + q];    // 4 KiB codebook, L1-resident
        float4 xv = xr[q];
        float4 r;
        r.x = xv.x - c.x; r.y = xv.y - c.y;
        r.z = xv.z - c.z; r.w = xv.w - c.w;
        s4[(tid << 4) + (q ^ (tid & 15))] = r;
    }
    __syncthreads();

    // ---- Phase 3: coalesced residual store (1KiB/wave/instr) ----
    const size_t rbase = (size_t)NTOK * (K / 4) + blk4;
#pragma unroll
    for (int it = 0; it < ROW4; ++it) {
        int i   = it * TPB + tid;
        int tok = i >> 4, q = i & 15;
        out4[rbase + i] = s4[(tok << 4) + (q ^ (tok & 15))];
    }

    // ---- Phase 4: onehot via wave shuffle, fully coalesced, no LDS ----
    const int lane      = tid & 63;
    const int wtokbase  = blockIdx.x * TPB + (tid & ~63);  // wave's first token
    const size_t ohbase = (size_t)wtokbase * (K / 4);      // float4 units
#pragma unroll
    for (int it = 0; it < 4; ++it) {
        int j = it * 64 + lane;          // float4 idx within wave's 256
        int srclane = j >> 2;            // owner lane of that token (0..63)
        int sub = j & 3;
        int b = __shfl(bidx, srclane);
        float4 v;
        v.x = (b == sub * 4 + 0) ? 1.f : 0.f;
        v.y = (b == sub * 4 + 1) ? 1.f : 0.f;
        v.z = (b == sub * 4 + 2) ? 1.f : 0.f;
        v.w = (b == sub * 4 + 3) ? 1.f : 0.f;
        out4[ohbase + j] = v;
    }
}

extern "C" void kernel_launch(void* const* d_in, const int* in_sizes, int n_in,
                              void* d_out, int out_size, void* d_ws, size_t ws_size,
                              hipStream_t stream) {
    const float* x  = (const float*)d_in[0];   // [262144, 64] fp32
    const float* cb = (const float*)d_in[1];   // [16, 64] fp32
    float* out = (float*)d_out;                // [N*16 onehot | N*64 residual] fp32

    quantizer_kernel<<<NTOK / TPB, TPB, 0, stream>>>(x, cb, out);
}

// Round 5
// 48.040 us; speedup vs baseline: 1.5989x; 1.0678x over previous
//
#include <hip/hip_runtime.h>

constexpr int NTOK = 262144;
constexpr int D    = 64;   // CODE_DIM
constexpr int K    = 16;   // NUM_CODES
constexpr int TPB  = 256;
constexpr int ROW4 = D / 4;          // 16 float4 per token row

__global__ __launch_bounds__(TPB) void quantizer_kernel(
    const float* __restrict__ x, const float* __restrict__ cb, float* __restrict__ out)
{
    const int tid  = threadIdx.x;
    const int lane = tid & 63;
    const int t    = blockIdx.x * TPB + tid;          // this thread's token

    const float4* __restrict__ X4  = reinterpret_cast<const float4*>(x);
    const float4* __restrict__ CB4 = reinterpret_cast<const float4*>(cb);
    float4* __restrict__ out4      = reinterpret_cast<float4*>(out);

    // ---- Pass A: own token row, strided loads (lines fully consumed across wave) ----
    float4 xr[ROW4];
#pragma unroll
    for (int q = 0; q < ROW4; ++q) xr[q] = X4[(size_t)t * ROW4 + q];

    // ---- distances: fp32 16-dim sequential partials, f64 sequential accumulate;
    //      strict-< first-occurrence argmin. BIT-IDENTICAL to R2/R3 (absmax==0). ----
    double best = 1e300;
    int bidx = 0;
#pragma unroll
    for (int k = 0; k < K; ++k) {
        double a = 0.0;
#pragma unroll
        for (int b = 0; b < 4; ++b) {
            float p = 0.f;
#pragma unroll
            for (int j = 0; j < 4; ++j) {
                float4 c  = CB4[k * ROW4 + b * 4 + j];   // wave-uniform -> scalar K$
                float4 xv = xr[b * 4 + j];
                float d0 = xv.x - c.x, d1 = xv.y - c.y;
                float d2 = xv.z - c.z, d3 = xv.w - c.w;
                p = fmaf(d0, d0, p);
                p = fmaf(d1, d1, p);
                p = fmaf(d2, d2, p);
                p = fmaf(d3, d3, p);
            }
            a += (double)p;
        }
        if (a < best) { best = a; bidx = k; }
    }

    // ---- Residual: wave-transposed coalesced stores, no LDS/barriers.
    //      Wave region = 64 tokens * 16 float4 = 1024 float4 -> 16 iters of 64 lanes.
    //      float4 i=j*64+lane -> token-in-wave (i>>4)=j*4+(lane>>4), quarter (i&15)=lane&15. ----
    const int wtokbase  = blockIdx.x * TPB + (tid & ~63);     // wave's first token
    const size_t rbase  = (size_t)NTOK * (K / 4) + (size_t)wtokbase * ROW4;
    const size_t xbase  = (size_t)wtokbase * ROW4;
    const int q = lane & 15;
#pragma unroll
    for (int j = 0; j < 16; ++j) {
        const int srclane = j * 4 + (lane >> 4);              // owner lane of token i>>4
        const int b  = __shfl(bidx, srclane);
        float4 xv = X4[xbase + j * 64 + lane];                // coalesced re-load, L2-hot
        float4 c  = CB4[b * ROW4 + q];                        // 4 KiB codebook, L1-resident
        float4 r;
        r.x = xv.x - c.x; r.y = xv.y - c.y;
        r.z = xv.z - c.z; r.w = xv.w - c.w;
        out4[rbase + j * 64 + lane] = r;
    }

    // ---- Onehot: wave region = 64 tokens * 4 float4 = 256 float4 -> 4 iters.
    //      float4 i=j*64+lane -> token-in-wave (i>>2)=j*16+(lane>>2), sub (i&3)=lane&3. ----
    const size_t ohbase = (size_t)wtokbase * (K / 4);
    const int sub = lane & 3;
#pragma unroll
    for (int j = 0; j < 4; ++j) {
        const int srclane = j * 16 + (lane >> 2);
        const int b = __shfl(bidx, srclane);
        float4 v;
        v.x = (b == sub * 4 + 0) ? 1.f : 0.f;
        v.y = (b == sub * 4 + 1) ? 1.f : 0.f;
        v.z = (b == sub * 4 + 2) ? 1.f : 0.f;
        v.w = (b == sub * 4 + 3) ? 1.f : 0.f;
        out4[ohbase + j * 64 + lane] = v;
    }
}

extern "C" void kernel_launch(void* const* d_in, const int* in_sizes, int n_in,
                              void* d_out, int out_size, void* d_ws, size_t ws_size,
                              hipStream_t stream) {
    const float* x  = (const float*)d_in[0];   // [262144, 64] fp32
    const float* cb = (const float*)d_in[1];   // [16, 64] fp32
    float* out = (float*)d_out;                // [N*16 onehot | N*64 residual] fp32

    quantizer_kernel<<<NTOK / TPB, TPB, 0, stream>>>(x, cb, out);
}